// Round 1
// baseline (6919.032 us; speedup 1.0000x reference)
//
#include <hip/hip_runtime.h>
#include <cstdint>
#include <cstddef>

#define B_  64
#define T_  512
#define I_  512
#define H_  1024

typedef float  f32x4  __attribute__((ext_vector_type(4)));
typedef __bf16 bf16x8 __attribute__((ext_vector_type(8)));
typedef unsigned short us4v __attribute__((ext_vector_type(4)));

__device__ __forceinline__ unsigned short f2bf(float f) {
  unsigned int u = __float_as_uint(f);
  u = (u + 0x7fffu + ((u >> 16) & 1u)) >> 16;   // round-to-nearest-even
  return (unsigned short)u;
}

__device__ __forceinline__ float fast_tanh(float x) {
  x = fminf(10.f, fmaxf(-10.f, x));             // avoid inf/inf -> NaN
  float e = __expf(2.f * x);
  return (e - 1.f) / (e + 1.f);
}

// ---------------------------------------------------------------------------
// Transpose fp32 [R][C] -> bf16 [C][R] (K-major layouts for MFMA B-operands)
// ---------------------------------------------------------------------------
__global__ __launch_bounds__(256) void k_transpose_cvt(
    const float* __restrict__ in, unsigned short* __restrict__ out, int R, int C) {
  __shared__ float tile[64][65];
  const int tx = threadIdx.x & 63, ty = threadIdx.x >> 6;
  const int c0 = blockIdx.x * 64, r0 = blockIdx.y * 64;
#pragma unroll
  for (int i = 0; i < 16; i++) {
    int r = i * 4 + ty;
    tile[r][tx] = in[(size_t)(r0 + r) * C + c0 + tx];
  }
  __syncthreads();
#pragma unroll
  for (int i = 0; i < 16; i++) {
    int c = i * 4 + ty;
    out[(size_t)(c0 + c) * R + r0 + tx] = f2bf(tile[tx][c]);
  }
}

// ---------------------------------------------------------------------------
// bias = b_ih + b_hh ; zero the sync counters (ws is poisoned every launch)
// grid 8 x 256 = 2048 threads; cnt has 4*512 = 2048 entries
// ---------------------------------------------------------------------------
__global__ __launch_bounds__(256) void k_prep(
    const float* __restrict__ bih, const float* __restrict__ bhh,
    float* __restrict__ bias, unsigned int* __restrict__ cnt) {
  int gid = blockIdx.x * 256 + threadIdx.x;
  if (gid < H_) bias[gid] = bih[gid] + bhh[gid];
  cnt[gid] = 0u;
}

// ---------------------------------------------------------------------------
// Phase 1: xw = x @ w_ih + bias  -> written into d_out's hidden_seq region
// [32768 x 512] @ [512 x 1024], 128x128 tiles, 4 waves, 16x16x32 bf16 MFMA
// ---------------------------------------------------------------------------
__global__ __launch_bounds__(256) void k_gemm_xw(
    const float* __restrict__ x, const unsigned short* __restrict__ wihT,
    const float* __restrict__ bias, float* __restrict__ out) {
  __shared__ __align__(16) unsigned short As[128 * 40];  // [m][k] padded 32->40
  __shared__ __align__(16) unsigned short Bs[128 * 40];  // [n][k] padded

  const int tid = threadIdx.x;
  const int tileM = blockIdx.x >> 3;
  const int tileN = blockIdx.x & 7;
  const int wv = tid >> 6, lane = tid & 63;
  const int row16 = lane & 15, quad = lane >> 4;
  const int m0 = (wv & 1) * 64, n0 = (wv >> 1) * 64;

  f32x4 acc[4][4];
#pragma unroll
  for (int i = 0; i < 4; i++)
#pragma unroll
    for (int j = 0; j < 4; j++) acc[i][j] = (f32x4){0.f, 0.f, 0.f, 0.f};

  const int ar = tid >> 3;            // 0..31
  const int ac = (tid & 7) << 2;      // 0..28 step 4
  const int br = tid >> 2;            // 0..63
  const int bc = (tid & 3) << 3;      // 0,8,16,24

#pragma unroll 1
  for (int kt = 0; kt < I_ / 32; kt++) {
    const int k0 = kt * 32;
    // stage A: x fp32 -> bf16 LDS
#pragma unroll
    for (int i = 0; i < 4; i++) {
      int r = ar + i * 32;
      float4 v = *(const float4*)(x + (size_t)(tileM * 128 + r) * I_ + k0 + ac);
      us4v o;
      o.x = f2bf(v.x); o.y = f2bf(v.y); o.z = f2bf(v.z); o.w = f2bf(v.w);
      *(us4v*)(As + r * 40 + ac) = o;
    }
    // stage B: wihT already bf16 K-major
#pragma unroll
    for (int i = 0; i < 2; i++) {
      int r = br + i * 64;
      *(uint4*)(Bs + r * 40 + bc) =
          *(const uint4*)(wihT + (size_t)(tileN * 128 + r) * I_ + k0 + bc);
    }
    __syncthreads();

    bf16x8 af[4], bfr[4];
#pragma unroll
    for (int mt = 0; mt < 4; mt++)
      af[mt] = *(const bf16x8*)(As + (m0 + mt * 16 + row16) * 40 + quad * 8);
#pragma unroll
    for (int nt = 0; nt < 4; nt++)
      bfr[nt] = *(const bf16x8*)(Bs + (n0 + nt * 16 + row16) * 40 + quad * 8);
#pragma unroll
    for (int mt = 0; mt < 4; mt++)
#pragma unroll
      for (int nt = 0; nt < 4; nt++)
        acc[mt][nt] = __builtin_amdgcn_mfma_f32_16x16x32_bf16(
            af[mt], bfr[nt], acc[mt][nt], 0, 0, 0);
    __syncthreads();
  }

  // epilogue: + bias, fp32 store (C/D layout: row = quad*4+r, col = lane&15)
#pragma unroll
  for (int mt = 0; mt < 4; mt++)
#pragma unroll
    for (int nt = 0; nt < 4; nt++) {
      int gc = tileN * 128 + n0 + nt * 16 + row16;
      float bv = bias[gc];
#pragma unroll
      for (int r = 0; r < 4; r++) {
        int gr = tileM * 128 + m0 + mt * 16 + quad * 4 + r;
        out[(size_t)gr * H_ + gc] = acc[mt][nt][r] + bv;
      }
    }
}

// ---------------------------------------------------------------------------
// Phase 2: persistent recurrence. 64 blocks = 4 groups(16 batches) x 16
// column-blocks(64 cols). w_hh fragments stationary in registers
// (32 k-chunks x 4 VGPR = 128 VGPRs/lane). Per step: group-wide flag sync,
// stage h-slice to LDS, 32 MFMAs/wave, tanh, publish bf16 h (ping-pong).
// ---------------------------------------------------------------------------
__global__ __launch_bounds__(256, 1) void k_scan(
    const unsigned short* __restrict__ whhT,
    unsigned short* __restrict__ hbuf, unsigned int* __restrict__ cnt,
    float* __restrict__ out) {
  const int bid = blockIdx.x;
  const int g = bid >> 4, j = bid & 15;
  const int tid = threadIdx.x;
  const int wv = tid >> 6, lane = tid & 63;
  const int row = lane & 15, quad = lane >> 4;
  const int bsl = g * 16;                       // batch slice base
  const int mycol = j * 64 + wv * 16 + row;     // this lane's output column

  __shared__ __align__(16) unsigned short hs[16 * 1032];  // h-slice, padded
  unsigned int* cntg = cnt + g * 512;

  // stationary B-operand: whh[k][mycol], K-major, 32 chunks of K=32
  bf16x8 wfrag[32];
  {
    const unsigned short* wp = whhT + (size_t)mycol * H_ + quad * 8;
#pragma unroll
    for (int kk = 0; kk < 32; kk++)
      wfrag[kk] = *(const bf16x8*)(wp + kk * 32);
  }

  for (int t = 0; t < T_; ++t) {
    f32x4 acc = (f32x4){0.f, 0.f, 0.f, 0.f};
    if (t > 0) {
      if (tid == 0) {
        while (__hip_atomic_load(&cntg[t - 1], __ATOMIC_ACQUIRE,
                                 __HIP_MEMORY_SCOPE_AGENT) < 16u) {}
      }
      __syncthreads();
      __threadfence();   // acquire: invalidate stale L1 before reading hbuf
      const unsigned short* hsrc = hbuf + ((t - 1) & 1) * (B_ * H_) + bsl * H_;
#pragma unroll
      for (int i = 0; i < 8; i++) {
        int c = i * 256 + tid;            // 0..2047 16B-chunks
        int rr = c >> 7, kc = c & 127;
        *(uint4*)(hs + rr * 1032 + kc * 8) =
            *(const uint4*)(hsrc + rr * 1024 + kc * 8);
      }
      __syncthreads();
      const unsigned short* hrow = hs + row * 1032 + quad * 8;
#pragma unroll
      for (int kk = 0; kk < 32; kk++) {
        bf16x8 a = *(const bf16x8*)(hrow + kk * 32);
        acc = __builtin_amdgcn_mfma_f32_16x16x32_bf16(a, wfrag[kk], acc, 0, 0, 0);
      }
    }
    // epilogue: h = tanh(acc + xw) ; xw was pre-written into out by k_gemm_xw
    unsigned short* hdst = hbuf + (t & 1) * (B_ * H_);
#pragma unroll
    for (int r = 0; r < 4; r++) {
      int b = bsl + quad * 4 + r;
      size_t oi = ((size_t)b * T_ + t) * H_ + mycol;
      float v = acc[r] + out[oi];
      float h = fast_tanh(v);
      out[oi] = h;                                  // hidden_seq
      hdst[b * H_ + mycol] = f2bf(h);               // bf16 for next step
      if (t == T_ - 1)
        out[(size_t)B_ * T_ * H_ + (size_t)b * H_ + mycol] = h;  // h_T tail
    }
    __threadfence();   // release: drain our stores device-wide
    __syncthreads();   // whole block done writing
    if (tid == 0)
      __hip_atomic_fetch_add(&cntg[t], 1u, __ATOMIC_RELEASE,
                             __HIP_MEMORY_SCOPE_AGENT);
  }
}

// ---------------------------------------------------------------------------
extern "C" void kernel_launch(void* const* d_in, const int* in_sizes, int n_in,
                              void* d_out, int out_size, void* d_ws, size_t ws_size,
                              hipStream_t stream) {
  const float* x    = (const float*)d_in[0];
  const float* w_ih = (const float*)d_in[1];
  const float* w_hh = (const float*)d_in[2];
  const float* b_ih = (const float*)d_in[3];
  const float* b_hh = (const float*)d_in[4];
  float* out = (float*)d_out;

  char* ws = (char*)d_ws;
  // ws layout (all 16B aligned):
  unsigned short* whhT = (unsigned short*)(ws);                       // 2 MB
  unsigned short* wihT = (unsigned short*)(ws + (2u << 20));          // 1 MB
  float*          bias = (float*)(ws + (3u << 20));                   // 4 KB
  unsigned int*   cnt  = (unsigned int*)(ws + (3u << 20) + 4096);     // 8 KB
  unsigned short* hbuf = (unsigned short*)(ws + (3u << 20) + 4096 + 8192); // 256 KB

  // transpose+convert weights to bf16 K-major
  hipLaunchKernelGGL(k_transpose_cvt, dim3(H_ / 64, H_ / 64), dim3(256), 0, stream,
                     w_hh, whhT, H_, H_);
  hipLaunchKernelGGL(k_transpose_cvt, dim3(H_ / 64, I_ / 64), dim3(256), 0, stream,
                     w_ih, wihT, I_, H_);
  hipLaunchKernelGGL(k_prep, dim3(8), dim3(256), 0, stream, b_ih, b_hh, bias, cnt);
  // phase 1: xw (+bias) into d_out hidden_seq region
  hipLaunchKernelGGL(k_gemm_xw, dim3((B_ * T_ / 128) * (H_ / 128)), dim3(256), 0,
                     stream, x, wihT, bias, out);
  // phase 2: sequential scan, in-place tanh over d_out
  hipLaunchKernelGGL(k_scan, dim3(64), dim3(256), 0, stream, whhT, hbuf, cnt, out);
}

// Round 2
// 5728.970 us; speedup vs baseline: 1.2077x; 1.2077x over previous
//
#include <hip/hip_runtime.h>
#include <cstdint>
#include <cstddef>

#define B_  64
#define T_  512
#define I_  512
#define H_  1024

typedef float  f32x4  __attribute__((ext_vector_type(4)));
typedef __bf16 bf16x8 __attribute__((ext_vector_type(8)));
typedef unsigned short us4v __attribute__((ext_vector_type(4)));
typedef unsigned long long u64x2 __attribute__((ext_vector_type(2)));
typedef unsigned long long ull;

__device__ __forceinline__ unsigned short f2bf(float f) {
  unsigned int u = __float_as_uint(f);
  u = (u + 0x7fffu + ((u >> 16) & 1u)) >> 16;   // round-to-nearest-even
  return (unsigned short)u;
}

__device__ __forceinline__ float fast_tanh(float x) {
  x = fminf(10.f, fmaxf(-10.f, x));
  float e = __expf(2.f * x);
  return (e - 1.f) * __builtin_amdgcn_rcpf(e + 1.f);
}

// Relaxed agent-scope atomics: coherent through L3, NO cache-maintenance ops.
__device__ __forceinline__ void st_ag64(ull* p, ull v) {
  __hip_atomic_store(p, v, __ATOMIC_RELAXED, __HIP_MEMORY_SCOPE_AGENT);
}
__device__ __forceinline__ ull ld_ag64(const ull* p) {
  return __hip_atomic_load(p, __ATOMIC_RELAXED, __HIP_MEMORY_SCOPE_AGENT);
}
__device__ __forceinline__ void st_ag32(unsigned int* p, unsigned int v) {
  __hip_atomic_store(p, v, __ATOMIC_RELAXED, __HIP_MEMORY_SCOPE_AGENT);
}
__device__ __forceinline__ unsigned int ld_ag32(const unsigned int* p) {
  return __hip_atomic_load(p, __ATOMIC_RELAXED, __HIP_MEMORY_SCOPE_AGENT);
}

// ---------------------------------------------------------------------------
// Transpose fp32 [R][C] -> bf16 [C][R] (K-major layouts for MFMA B-operands)
// ---------------------------------------------------------------------------
__global__ __launch_bounds__(256) void k_transpose_cvt(
    const float* __restrict__ in, unsigned short* __restrict__ out, int R, int C) {
  __shared__ float tile[64][65];
  const int tx = threadIdx.x & 63, ty = threadIdx.x >> 6;
  const int c0 = blockIdx.x * 64, r0 = blockIdx.y * 64;
#pragma unroll
  for (int i = 0; i < 16; i++) {
    int r = i * 4 + ty;
    tile[r][tx] = in[(size_t)(r0 + r) * C + c0 + tx];
  }
  __syncthreads();
#pragma unroll
  for (int i = 0; i < 16; i++) {
    int c = i * 4 + ty;
    out[(size_t)(c0 + c) * R + r0 + tx] = f2bf(tile[tx][c]);
  }
}

// ---------------------------------------------------------------------------
// bias = b_ih + b_hh ; zero flags (ws is poisoned 0xAA every launch)
// ---------------------------------------------------------------------------
__global__ __launch_bounds__(256) void k_prep(
    const float* __restrict__ bih, const float* __restrict__ bhh,
    float* __restrict__ bias, unsigned int* __restrict__ cnt) {
  int gid = blockIdx.x * 256 + threadIdx.x;
  if (gid < H_) bias[gid] = bih[gid] + bhh[gid];
  cnt[gid] = 0u;
}

// ---------------------------------------------------------------------------
// Phase 1: xw = x @ w_ih + bias  -> written into d_out's hidden_seq region
// ---------------------------------------------------------------------------
__global__ __launch_bounds__(256) void k_gemm_xw(
    const float* __restrict__ x, const unsigned short* __restrict__ wihT,
    const float* __restrict__ bias, float* __restrict__ out) {
  __shared__ __align__(16) unsigned short As[128 * 40];
  __shared__ __align__(16) unsigned short Bs[128 * 40];

  const int tid = threadIdx.x;
  const int tileM = blockIdx.x >> 3;
  const int tileN = blockIdx.x & 7;
  const int wv = tid >> 6, lane = tid & 63;
  const int row16 = lane & 15, quad = lane >> 4;
  const int m0 = (wv & 1) * 64, n0 = (wv >> 1) * 64;

  f32x4 acc[4][4];
#pragma unroll
  for (int i = 0; i < 4; i++)
#pragma unroll
    for (int j = 0; j < 4; j++) acc[i][j] = (f32x4){0.f, 0.f, 0.f, 0.f};

  const int ar = tid >> 3, ac = (tid & 7) << 2;
  const int br = tid >> 2, bc = (tid & 3) << 3;

#pragma unroll 1
  for (int kt = 0; kt < I_ / 32; kt++) {
    const int k0 = kt * 32;
#pragma unroll
    for (int i = 0; i < 4; i++) {
      int r = ar + i * 32;
      float4 v = *(const float4*)(x + (size_t)(tileM * 128 + r) * I_ + k0 + ac);
      us4v o;
      o.x = f2bf(v.x); o.y = f2bf(v.y); o.z = f2bf(v.z); o.w = f2bf(v.w);
      *(us4v*)(As + r * 40 + ac) = o;
    }
#pragma unroll
    for (int i = 0; i < 2; i++) {
      int r = br + i * 64;
      *(uint4*)(Bs + r * 40 + bc) =
          *(const uint4*)(wihT + (size_t)(tileN * 128 + r) * I_ + k0 + bc);
    }
    __syncthreads();

    bf16x8 af[4], bfr[4];
#pragma unroll
    for (int mt = 0; mt < 4; mt++)
      af[mt] = *(const bf16x8*)(As + (m0 + mt * 16 + row16) * 40 + quad * 8);
#pragma unroll
    for (int nt = 0; nt < 4; nt++)
      bfr[nt] = *(const bf16x8*)(Bs + (n0 + nt * 16 + row16) * 40 + quad * 8);
#pragma unroll
    for (int mt = 0; mt < 4; mt++)
#pragma unroll
      for (int nt = 0; nt < 4; nt++)
        acc[mt][nt] = __builtin_amdgcn_mfma_f32_16x16x32_bf16(
            af[mt], bfr[nt], acc[mt][nt], 0, 0, 0);
    __syncthreads();
  }

#pragma unroll
  for (int mt = 0; mt < 4; mt++)
#pragma unroll
    for (int nt = 0; nt < 4; nt++) {
      int gc = tileN * 128 + n0 + nt * 16 + row16;
      float bv = bias[gc];
#pragma unroll
      for (int r = 0; r < 4; r++) {
        int gr = tileM * 128 + m0 + mt * 16 + quad * 4 + r;
        out[(size_t)gr * H_ + gc] = acc[mt][nt][r] + bv;
      }
    }
}

// ---------------------------------------------------------------------------
// Phase 2: persistent recurrence, FENCE-FREE message passing.
// 64 blocks = 4 groups(16 batches) x 16 column-chunks(64 cols).
// w_hh column fragments stationary in registers (128 VGPRs/lane).
// Cross-block h exchange via relaxed agent-scope atomics (sc1 -> L3-coherent,
// zero cache-maintenance). Per-WAVE flags: no __syncthreads in the loop.
//
// hbuf layout (ull units): slot s(2) x group g(4) x chunk j(16) x row b(16)
//   x 64 bf16 cols.  chunk = 256 ull; group = 4096 ull; slot = 16384 ull.
// flag[g*64 + j*4 + wv] = t+1  once that wave's h_t sub-tile is in L3.
// ---------------------------------------------------------------------------
__global__ __launch_bounds__(256, 1) void k_scan(
    const unsigned short* __restrict__ whhT,
    unsigned short* __restrict__ hbuf, unsigned int* __restrict__ cnt,
    float* __restrict__ out) {
  const int bid = blockIdx.x;
  const int g = bid >> 4, j = bid & 15;
  const int tid = threadIdx.x;
  const int wv = tid >> 6, lane = tid & 63;
  const int row = lane & 15, quad = lane >> 4;
  const int bsl = g * 16;                       // batch slice base
  const int mycol = j * 64 + wv * 16 + row;     // this lane's output column

  ull* hb = (ull*)hbuf;
  unsigned int* flg = cnt + g * 64;

  // stationary B-operand: whh[k][mycol], K-major, 32 chunks of K=32
  bf16x8 wfrag[32];
  {
    const unsigned short* wp = whhT + (size_t)mycol * H_ + quad * 8;
#pragma unroll
    for (int kk = 0; kk < 32; kk++)
      wfrag[kk] = *(const bf16x8*)(wp + kk * 32);
  }

  // producer store address (ull units): col0 = wv*16 + (row&~3)
  const int pst = g * 4096 + j * 256 + wv * 4 + (row >> 2);  // + b*16 + slot
  // consumer load base (ull units): + slot + kb*256
  const int cld = g * 4096 + row * 16 + quad * 2;

  for (int t = 0; t < T_; ++t) {
    // prefetch xw early (plain cacheable loads; written by k_gemm_xw)
    float xwv[4];
    size_t oi[4];
#pragma unroll
    for (int r = 0; r < 4; r++) {
      int b = bsl + quad * 4 + r;
      oi[r] = ((size_t)b * T_ + t) * H_ + mycol;
      xwv[r] = out[oi[r]];
    }

    f32x4 acc[4];
#pragma unroll
    for (int c = 0; c < 4; c++) acc[c] = (f32x4){0.f, 0.f, 0.f, 0.f};

    if (t > 0) {
      // per-wave spin: all 64 flags of this group must reach t
      const unsigned int tgt = (unsigned int)t;
      while (true) {
        unsigned int f = ld_ag32(flg + lane);
        if (__ballot(f >= tgt) == ~0ull) break;
      }
      // issue ALL h loads back-to-back (pipelined L3 latency)
      const ull* base = hb + ((t - 1) & 1) * 16384 + cld;
      u64x2 va[32];
#pragma unroll
      for (int kb = 0; kb < 16; kb++) {
        const ull* cp = base + kb * 256;
        va[2 * kb].x     = ld_ag64(cp);
        va[2 * kb].y     = ld_ag64(cp + 1);
        va[2 * kb + 1].x = ld_ag64(cp + 8);
        va[2 * kb + 1].y = ld_ag64(cp + 9);
      }
      // 4 independent accumulator chains -> issue-bound MFMA
#pragma unroll
      for (int kb = 0; kb < 16; kb++) {
        bf16x8 a0 = __builtin_bit_cast(bf16x8, va[2 * kb]);
        bf16x8 a1 = __builtin_bit_cast(bf16x8, va[2 * kb + 1]);
        acc[kb & 3] = __builtin_amdgcn_mfma_f32_16x16x32_bf16(
            a0, wfrag[2 * kb], acc[kb & 3], 0, 0, 0);
        acc[kb & 3] = __builtin_amdgcn_mfma_f32_16x16x32_bf16(
            a1, wfrag[2 * kb + 1], acc[kb & 3], 0, 0, 0);
      }
    }
    f32x4 accf = (acc[0] + acc[1]) + (acc[2] + acc[3]);

    // epilogue: h = tanh(acc + xw); publish bf16 h packed to 8B via shfl
    ull* pbase = hb + (t & 1) * 16384 + pst;
#pragma unroll
    for (int r = 0; r < 4; r++) {
      float h = fast_tanh(accf[r] + xwv[r]);
      out[oi[r]] = h;                               // hidden_seq
      if (t == T_ - 1) {
        int b = bsl + quad * 4 + r;
        out[(size_t)B_ * T_ * H_ + (size_t)b * H_ + mycol] = h;  // h_T
      }
      unsigned int myu = (unsigned int)f2bf(h);
      unsigned int pr  = __shfl_xor(myu, 1);
      unsigned int pair = (lane & 1) ? 0u : (myu | (pr << 16));
      unsigned int hi  = __shfl_xor(pair, 2);
      if ((lane & 3) == 0) {
        ull q = (ull)pair | ((ull)hi << 32);
        int b = quad * 4 + r;
        st_ag64(pbase + b * 16, q);
      }
    }
    // order: h stores acked at L3, then flag
    __builtin_amdgcn_s_waitcnt(0);
    if (lane == 0) st_ag32(&flg[j * 4 + wv], (unsigned int)(t + 1));
  }
}

// ---------------------------------------------------------------------------
extern "C" void kernel_launch(void* const* d_in, const int* in_sizes, int n_in,
                              void* d_out, int out_size, void* d_ws, size_t ws_size,
                              hipStream_t stream) {
  const float* x    = (const float*)d_in[0];
  const float* w_ih = (const float*)d_in[1];
  const float* w_hh = (const float*)d_in[2];
  const float* b_ih = (const float*)d_in[3];
  const float* b_hh = (const float*)d_in[4];
  float* out = (float*)d_out;

  char* ws = (char*)d_ws;
  unsigned short* whhT = (unsigned short*)(ws);                       // 2 MB
  unsigned short* wihT = (unsigned short*)(ws + (2u << 20));          // 1 MB
  float*          bias = (float*)(ws + (3u << 20));                   // 4 KB
  unsigned int*   cnt  = (unsigned int*)(ws + (3u << 20) + 4096);     // 8 KB
  unsigned short* hbuf = (unsigned short*)(ws + (3u << 20) + 4096 + 8192); // 256 KB

  hipLaunchKernelGGL(k_transpose_cvt, dim3(H_ / 64, H_ / 64), dim3(256), 0, stream,
                     w_hh, whhT, H_, H_);
  hipLaunchKernelGGL(k_transpose_cvt, dim3(H_ / 64, I_ / 64), dim3(256), 0, stream,
                     w_ih, wihT, I_, H_);
  hipLaunchKernelGGL(k_prep, dim3(8), dim3(256), 0, stream, b_ih, b_hh, bias, cnt);
  hipLaunchKernelGGL(k_gemm_xw, dim3((B_ * T_ / 128) * (H_ / 128)), dim3(256), 0,
                     stream, x, wihT, bias, out);
  hipLaunchKernelGGL(k_scan, dim3(64), dim3(256), 0, stream, whhT, hbuf, cnt, out);
}